// Round 1
// baseline (316.186 us; speedup 1.0000x reference)
//
#include <hip/hip_runtime.h>

#define HH_EPS 1e-8f

constexpr int D      = 2048;            // feature dim
constexpr int K      = 16;              // number of reflections
constexpr int R      = 4;               // rows per wave
constexpr int CHUNKS = D / (64 * 4);    // 8 float4 chunks per lane per row
constexpr int NROWS  = 4 * 4096;        // B * S = 16384

// Prologue: c[k] = 2 / max(dot(v_k, v_k), EPS). One wave per vector.
__global__ void __launch_bounds__(64) hh_norms_kernel(const float* __restrict__ vecs,
                                                      float* __restrict__ c) {
    int k = blockIdx.x;
    int lane = threadIdx.x;           // 0..63
    const float4* v4 = (const float4*)(vecs + k * D);
    float s = 0.f;
#pragma unroll
    for (int j = 0; j < CHUNKS; ++j) {
        float4 v = v4[j * 64 + lane];
        s += v.x * v.x + v.y * v.y + v.z * v.z + v.w * v.w;
    }
#pragma unroll
    for (int off = 32; off >= 1; off >>= 1)
        s += __shfl_xor(s, off);
    if (lane == 0) c[k] = 2.0f / fmaxf(s, HH_EPS);
}

// Main: each wave owns R consecutive rows of h, held entirely in registers
// across all K reflections. Per reflection: dot (per-lane partial over its
// 32 elements), 6-step shfl_xor wave reduction, rank-1 update.
__global__ void __launch_bounds__(256) hh_apply_kernel(const float* __restrict__ h_in,
                                                       const float* __restrict__ vecs,
                                                       const float* __restrict__ c,
                                                       float* __restrict__ h_out) {
    int wave = (int)((blockIdx.x * blockDim.x + threadIdx.x) >> 6);
    int lane = threadIdx.x & 63;
    int base_row = wave * R;

    // Load R rows into registers: coalesced 1 KiB-per-chunk float4 loads.
    float4 h[R][CHUNKS];
#pragma unroll
    for (int r = 0; r < R; ++r) {
        const float4* row = (const float4*)(h_in + (size_t)(base_row + r) * D);
#pragma unroll
        for (int j = 0; j < CHUNKS; ++j)
            h[r][j] = row[j * 64 + lane];
    }

    for (int k = 0; k < K; ++k) {
        const float4* v4 = (const float4*)(vecs + k * D);
        float4 v[CHUNKS];
        float dot[R];
#pragma unroll
        for (int r = 0; r < R; ++r) dot[r] = 0.f;

#pragma unroll
        for (int j = 0; j < CHUNKS; ++j) {
            v[j] = v4[j * 64 + lane];
#pragma unroll
            for (int r = 0; r < R; ++r) {
                dot[r] += h[r][j].x * v[j].x + h[r][j].y * v[j].y
                        + h[r][j].z * v[j].z + h[r][j].w * v[j].w;
            }
        }

        // Wave-wide reduction of R dots (64 lanes -> all lanes hold total).
#pragma unroll
        for (int off = 32; off >= 1; off >>= 1) {
#pragma unroll
            for (int r = 0; r < R; ++r)
                dot[r] += __shfl_xor(dot[r], off);
        }

        float ck = c[k];              // uniform scalar load
        float t[R];
#pragma unroll
        for (int r = 0; r < R; ++r) t[r] = ck * dot[r];

#pragma unroll
        for (int j = 0; j < CHUNKS; ++j) {
#pragma unroll
            for (int r = 0; r < R; ++r) {
                h[r][j].x -= t[r] * v[j].x;
                h[r][j].y -= t[r] * v[j].y;
                h[r][j].z -= t[r] * v[j].z;
                h[r][j].w -= t[r] * v[j].w;
            }
        }
    }

    // Write back.
#pragma unroll
    for (int r = 0; r < R; ++r) {
        float4* row = (float4*)(h_out + (size_t)(base_row + r) * D);
#pragma unroll
        for (int j = 0; j < CHUNKS; ++j)
            row[j * 64 + lane] = h[r][j];
    }
}

extern "C" void kernel_launch(void* const* d_in, const int* in_sizes, int n_in,
                              void* d_out, int out_size, void* d_ws, size_t ws_size,
                              hipStream_t stream) {
    const float* h    = (const float*)d_in[0];   // [4,4096,2048] fp32
    const float* vecs = (const float*)d_in[1];   // [16,2048] fp32
    float* out        = (float*)d_out;           // [4,4096,2048] fp32
    float* c          = (float*)d_ws;            // 16 floats scratch

    hh_norms_kernel<<<K, 64, 0, stream>>>(vecs, c);

    int waves  = NROWS / R;                      // 4096 waves
    int blocks = waves * 64 / 256;               // 1024 blocks of 4 waves
    hh_apply_kernel<<<blocks, 256, 0, stream>>>(h, vecs, c, out);
}

// Round 2
// 302.752 us; speedup vs baseline: 1.0444x; 1.0444x over previous
//
#include <hip/hip_runtime.h>

#define HH_EPS 1e-8f

constexpr int D      = 2048;            // feature dim
constexpr int K      = 16;              // number of reflections
constexpr int R      = 4;               // rows per wave
constexpr int CHUNKS = D / (64 * 4);    // 8 float4 chunks per lane per row
constexpr int NROWS  = 4 * 4096;        // B * S = 16384

// Prologue: c[k] = 2 / max(dot(v_k, v_k), EPS). One wave per vector.
__global__ void __launch_bounds__(64) hh_norms_kernel(const float* __restrict__ vecs,
                                                      float* __restrict__ c) {
    int k = blockIdx.x;
    int lane = threadIdx.x;           // 0..63
    const float4* v4 = (const float4*)(vecs + k * D);
    float s = 0.f;
#pragma unroll
    for (int j = 0; j < CHUNKS; ++j) {
        float4 v = v4[j * 64 + lane];
        s += v.x * v.x + v.y * v.y + v.z * v.z + v.w * v.w;
    }
#pragma unroll
    for (int off = 32; off >= 1; off >>= 1)
        s += __shfl_xor(s, off);
    if (lane == 0) c[k] = 2.0f / fmaxf(s, HH_EPS);
}

// One reflection phase: uses vcur (already in regs), prefetches the next
// vector into vnext so its L2 latency hides under this phase's VALU work.
__device__ __forceinline__ void hh_phase(float4 (&h)[R][CHUNKS],
                                         float4 (&vcur)[CHUNKS],
                                         float4 (&vnext)[CHUNKS],
                                         const float4* __restrict__ v4base,
                                         const float* __restrict__ c,
                                         int k, int lane) {
    // Prefetch v_{k+1} (wraps harmlessly to row 0 on the last phase).
    const float4* vn = v4base + ((k + 1) & 15) * (D / 4);
#pragma unroll
    for (int j = 0; j < CHUNKS; ++j)
        vnext[j] = vn[j * 64 + lane];

    // Uniform scalar load; result needed only after dot+reduce (~400 cyc).
    float ck = c[k];

    // Per-lane partial dots for R rows.
    float dot[R];
#pragma unroll
    for (int r = 0; r < R; ++r) dot[r] = 0.f;
#pragma unroll
    for (int j = 0; j < CHUNKS; ++j) {
#pragma unroll
        for (int r = 0; r < R; ++r) {
            dot[r] += h[r][j].x * vcur[j].x + h[r][j].y * vcur[j].y
                    + h[r][j].z * vcur[j].z + h[r][j].w * vcur[j].w;
        }
    }

    // Wave-wide butterfly reduction; all lanes end with the full sums.
#pragma unroll
    for (int off = 32; off >= 1; off >>= 1) {
#pragma unroll
        for (int r = 0; r < R; ++r)
            dot[r] += __shfl_xor(dot[r], off);
    }

    float t[R];
#pragma unroll
    for (int r = 0; r < R; ++r) t[r] = ck * dot[r];

    // Rank-1 update from registers.
#pragma unroll
    for (int j = 0; j < CHUNKS; ++j) {
#pragma unroll
        for (int r = 0; r < R; ++r) {
            h[r][j].x -= t[r] * vcur[j].x;
            h[r][j].y -= t[r] * vcur[j].y;
            h[r][j].z -= t[r] * vcur[j].z;
            h[r][j].w -= t[r] * vcur[j].w;
        }
    }
}

// Each wave owns R consecutive rows of h, held entirely in registers across
// all K reflections. launch_bounds(256,2): 256-VGPR budget -> no spills.
__global__ void __launch_bounds__(256, 2) hh_apply_kernel(const float* __restrict__ h_in,
                                                          const float* __restrict__ vecs,
                                                          const float* __restrict__ c,
                                                          float* __restrict__ h_out) {
    int wave = (int)((blockIdx.x * blockDim.x + threadIdx.x) >> 6);
    int lane = threadIdx.x & 63;
    int base_row = wave * R;

    // Load R rows into registers: coalesced float4 loads (1 KiB/chunk/wave).
    float4 h[R][CHUNKS];
#pragma unroll
    for (int r = 0; r < R; ++r) {
        const float4* row = (const float4*)(h_in + (size_t)(base_row + r) * D);
#pragma unroll
        for (int j = 0; j < CHUNKS; ++j)
            h[r][j] = row[j * 64 + lane];
    }

    const float4* v4base = (const float4*)vecs;

    // Preload v_0 into buffer A.
    float4 va[CHUNKS], vb[CHUNKS];
#pragma unroll
    for (int j = 0; j < CHUNKS; ++j)
        va[j] = v4base[j * 64 + lane];

    // Unroll-by-2 so the A/B register double-buffer resolves statically,
    // while keeping code size I$-friendly (no full 16x unroll).
#pragma unroll 1
    for (int k = 0; k < K; k += 2) {
        hh_phase(h, va, vb, v4base, c, k, lane);
        hh_phase(h, vb, va, v4base, c, k + 1, lane);
    }

    // Write back.
#pragma unroll
    for (int r = 0; r < R; ++r) {
        float4* row = (float4*)(h_out + (size_t)(base_row + r) * D);
#pragma unroll
        for (int j = 0; j < CHUNKS; ++j)
            row[j * 64 + lane] = h[r][j];
    }
}

extern "C" void kernel_launch(void* const* d_in, const int* in_sizes, int n_in,
                              void* d_out, int out_size, void* d_ws, size_t ws_size,
                              hipStream_t stream) {
    const float* h    = (const float*)d_in[0];   // [4,4096,2048] fp32
    const float* vecs = (const float*)d_in[1];   // [16,2048] fp32
    float* out        = (float*)d_out;           // [4,4096,2048] fp32
    float* c          = (float*)d_ws;            // 16 floats scratch

    hh_norms_kernel<<<K, 64, 0, stream>>>(vecs, c);

    int waves  = NROWS / R;                      // 4096 waves
    int blocks = waves * 64 / 256;               // 1024 blocks of 4 waves
    hh_apply_kernel<<<blocks, 256, 0, stream>>>(h, vecs, c, out);
}